// Round 1
// baseline (129.010 us; speedup 1.0000x reference)
//
#include <hip/hip_runtime.h>

#define N 8192
#define D 128
#define CHUNK 1024
#define NCHUNK (N / CHUNK)   // 8 column chunks
#define BITER (CHUNK / 128)  // 8 B-tiles per chunk

typedef unsigned short u16;
typedef __attribute__((ext_vector_type(8))) __bf16 bf16x8;
typedef __attribute__((ext_vector_type(4))) float f32x4;

__device__ __forceinline__ u16 f2bf(float x) {
  unsigned u = __float_as_uint(x);
  u += 0x7fff + ((u >> 16) & 1);   // round-to-nearest-even
  return (u16)(u >> 16);
}
__device__ __forceinline__ float bf2f(u16 h) {
  return __uint_as_float(((unsigned)h) << 16);
}

// XOR-swizzled LDS offset (u16 units): row r (0..127), 16B-chunk c (0..15).
// Breaks the 256B-row-stride 16-way bank conflict down to free 2-way.
__device__ __forceinline__ int swz(int r, int c) {
  return r * 128 + ((c ^ (r & 15)) << 3);
}

// ---------------- kernel 1: L2-normalize rows, split fp32 -> bf16 hi + lo ---
__global__ __launch_bounds__(256) void cpe_prep(const float* __restrict__ feat,
                                                u16* __restrict__ fhi,
                                                u16* __restrict__ flo) {
  const int w = threadIdx.x >> 6, l = threadIdx.x & 63;
  const int row = blockIdx.x * 4 + w;           // one wave per row
  const float2 x = *(const float2*)&feat[row * D + l * 2];
  float s = x.x * x.x + x.y * x.y;
#pragma unroll
  for (int sh = 1; sh < 64; sh <<= 1) s += __shfl_xor(s, sh);
  const float inv = 1.0f / fmaxf(sqrtf(s), 1e-12f);
  const float a = x.x * inv, b = x.y * inv;
  const u16 ah = f2bf(a), bh = f2bf(b);
  const u16 al = f2bf(a - bf2f(ah)), bl = f2bf(b - bf2f(bh));
  *(ushort2*)&fhi[row * D + l * 2] = make_ushort2(ah, bh);
  *(ushort2*)&flo[row * D + l * 2] = make_ushort2(al, bl);
}

// ---------------- kernel 2: fused sim + masked online reductions ------------
// Grid: (64 row-tiles of 128, 8 column chunks of 1024). Block 256 = 4 waves.
// Wave w owns rows [w*32, w*32+32) of the tile; A frags register-resident.
__global__ __launch_bounds__(256, 2) void cpe_main(
    const u16* __restrict__ fhi, const u16* __restrict__ flo,
    const int* __restrict__ labels, float4* __restrict__ partials) {
  __shared__ __align__(16) u16 Bh[128 * 128];   // 32 KB
  __shared__ __align__(16) u16 Bl[128 * 128];   // 32 KB
  const int rt = blockIdx.x, cc = blockIdx.y;
  const int tid = threadIdx.x;
  const int w = tid >> 6, l = tid & 63, q = l >> 4, m = l & 15;

  // ---- stage A tile through LDS once, pull fragments to registers
  {
    const int abase = rt * 128;
#pragma unroll
    for (int i = 0; i < 8; ++i) {
      const int idx = tid + i * 256;
      const int r = idx >> 4, c = idx & 15;
      *(uint4*)&Bh[swz(r, c)] = *(const uint4*)&fhi[(abase + r) * D + c * 8];
      *(uint4*)&Bl[swz(r, c)] = *(const uint4*)&flo[(abase + r) * D + c * 8];
    }
  }
  __syncthreads();
  // A-operand layout for mfma_f32_16x16x32_bf16: lane holds A[m=l&15][k=q*8+j]
  bf16x8 Ah[2][4], Al[2][4];
#pragma unroll
  for (int tr = 0; tr < 2; ++tr)
#pragma unroll
    for (int ks = 0; ks < 4; ++ks) {
      const int row = w * 32 + tr * 16 + m;
      Ah[tr][ks] = *(const bf16x8*)&Bh[swz(row, ks * 4 + q)];
      Al[tr][ks] = *(const bf16x8*)&Bl[swz(row, ks * 4 + q)];
    }
  __syncthreads();

  // labels of my 8 accumulator rows (C layout: row = q*4 + reg)
  int labi[2][4];
#pragma unroll
  for (int tr = 0; tr < 2; ++tr)
#pragma unroll
    for (int v = 0; v < 4; ++v)
      labi[tr][v] = labels[rt * 128 + w * 32 + tr * 16 + q * 4 + v];

  float mx[2][4], ps[2][4], as_[2][4], np[2][4];
#pragma unroll
  for (int tr = 0; tr < 2; ++tr)
#pragma unroll
    for (int v = 0; v < 4; ++v) {
      mx[tr][v] = -1e30f; ps[tr][v] = 0.f; as_[tr][v] = 0.f; np[tr][v] = 0.f;
    }

  for (int it = 0; it < BITER; ++it) {
    const int cbase = cc * CHUNK + it * 128;
#pragma unroll
    for (int i = 0; i < 8; ++i) {
      const int idx = tid + i * 256;
      const int r = idx >> 4, c = idx & 15;
      *(uint4*)&Bh[swz(r, c)] = *(const uint4*)&fhi[(cbase + r) * D + c * 8];
      *(uint4*)&Bl[swz(r, c)] = *(const uint4*)&flo[(cbase + r) * D + c * 8];
    }
    __syncthreads();

#pragma unroll
    for (int ct = 0; ct < 8; ++ct) {
      f32x4 acc0 = {0.f, 0.f, 0.f, 0.f}, acc1 = {0.f, 0.f, 0.f, 0.f};
#pragma unroll
      for (int ks = 0; ks < 4; ++ks) {
        const int row = ct * 16 + m;
        const bf16x8 bh = *(const bf16x8*)&Bh[swz(row, ks * 4 + q)];
        const bf16x8 bl = *(const bf16x8*)&Bl[swz(row, ks * 4 + q)];
        // bf16x3: hi*hi + hi*lo + lo*hi  (lo*lo term ~2^-18, dropped)
        acc0 = __builtin_amdgcn_mfma_f32_16x16x32_bf16(Ah[0][ks], bh, acc0, 0, 0, 0);
        acc1 = __builtin_amdgcn_mfma_f32_16x16x32_bf16(Ah[1][ks], bh, acc1, 0, 0, 0);
        acc0 = __builtin_amdgcn_mfma_f32_16x16x32_bf16(Ah[0][ks], bl, acc0, 0, 0, 0);
        acc1 = __builtin_amdgcn_mfma_f32_16x16x32_bf16(Ah[1][ks], bl, acc1, 0, 0, 0);
        acc0 = __builtin_amdgcn_mfma_f32_16x16x32_bf16(Al[0][ks], bh, acc0, 0, 0, 0);
        acc1 = __builtin_amdgcn_mfma_f32_16x16x32_bf16(Al[1][ks], bh, acc1, 0, 0, 0);
      }
      const int j = cbase + ct * 16 + m;       // C layout: col = lane&15
      const int labj = labels[j];
      const bool fgj = labj >= 0;
#pragma unroll
      for (int tr = 0; tr < 2; ++tr) {
#pragma unroll
        for (int v = 0; v < 4; ++v) {
          const float simv = (tr ? acc1[v] : acc0[v]) * 10.0f;  // /TEMPERATURE
          const int i_ = rt * 128 + w * 32 + tr * 16 + q * 4 + v;
          const float e = __expf(simv);        // sim in [-10,10], safe unshifted
          if (fgj && (j != i_)) {
            as_[tr][v] += e;
            mx[tr][v] = fmaxf(mx[tr][v], simv);
            if (labj == labi[tr][v]) { ps[tr][v] += e; np[tr][v] += 1.0f; }
          }
        }
      }
    }
    __syncthreads();
  }

  // reduce across the 16 lanes of each quad (they hold disjoint cols of one row)
#pragma unroll
  for (int tr = 0; tr < 2; ++tr)
#pragma unroll
    for (int v = 0; v < 4; ++v) {
      float vmx = mx[tr][v], vp = ps[tr][v], va = as_[tr][v], vn = np[tr][v];
#pragma unroll
      for (int s = 1; s < 16; s <<= 1) {
        vmx = fmaxf(vmx, __shfl_xor(vmx, s));
        vp += __shfl_xor(vp, s);
        va += __shfl_xor(va, s);
        vn += __shfl_xor(vn, s);
      }
      if (m == 0) {
        const int i_ = rt * 128 + w * 32 + tr * 16 + q * 4 + v;
        partials[cc * N + i_] = make_float4(vmx, vp, va, vn);
      }
    }
}

// ---------------- kernel 3: combine chunk partials -> per-row loss -> sums --
__global__ __launch_bounds__(256) void cpe_rows(const float4* __restrict__ partials,
                                                const int* __restrict__ labels,
                                                float* __restrict__ acc3) {
  const int r = blockIdx.x * 256 + threadIdx.x;
  float mx = -1e30f, ps = 0.f, as_ = 0.f, np = 0.f;
#pragma unroll
  for (int c = 0; c < NCHUNK; ++c) {
    const float4 p = partials[c * N + r];
    mx = fmaxf(mx, p.x); ps += p.y; as_ += p.z; np += p.w;
  }
  const float mcl = fminf(fmaxf(mx, -20.f), 20.f);
  const float sc = expf(-mcl);                   // apply shift analytically
  const float pos_sum = fminf(fmaxf(ps * sc, 1e-6f), 1e6f);
  const float all_sum = fminf(fmaxf(as_ * sc, 1e-6f), 1e6f);
  const float loss = fminf(-logf(pos_sum / all_sum), 10.0f);
  const bool fg = labels[r] >= 0;
  const bool valid = fg && (np > 0.5f);
  float v0 = valid ? loss : 0.f;
  float v1 = valid ? 1.f : 0.f;
  float v2 = fg ? 1.f : 0.f;
#pragma unroll
  for (int s = 1; s < 64; s <<= 1) {
    v0 += __shfl_xor(v0, s); v1 += __shfl_xor(v1, s); v2 += __shfl_xor(v2, s);
  }
  __shared__ float red[3][4];
  const int w = threadIdx.x >> 6, l = threadIdx.x & 63;
  if (l == 0) { red[0][w] = v0; red[1][w] = v1; red[2][w] = v2; }
  __syncthreads();
  if (threadIdx.x == 0) {
    atomicAdd(&acc3[0], red[0][0] + red[0][1] + red[0][2] + red[0][3]);
    atomicAdd(&acc3[1], red[1][0] + red[1][1] + red[1][2] + red[1][3]);
    atomicAdd(&acc3[2], red[2][0] + red[2][1] + red[2][2] + red[2][3]);
  }
}

// ---------------- kernel 4: scalar finalize --------------------------------
__global__ void cpe_final(const float* __restrict__ acc3, float* __restrict__ out) {
  const float ls = acc3[0], nv = acc3[1], nf = acc3[2];
  const bool ok = (nf >= 2.0f) && (nv > 0.0f);
  out[0] = ok ? ls / fmaxf(nv, 1.0f) : 0.0f;
}

extern "C" void kernel_launch(void* const* d_in, const int* in_sizes, int n_in,
                              void* d_out, int out_size, void* d_ws, size_t ws_size,
                              hipStream_t stream) {
  const float* feat = (const float*)d_in[0];
  const int* labels = (const int*)d_in[1];
  float* out = (float*)d_out;
  char* ws = (char*)d_ws;
  u16* fhi = (u16*)ws;                                        // 2 MB
  u16* flo = (u16*)(ws + (size_t)N * D * 2);                  // 2 MB
  float4* partials = (float4*)(ws + (size_t)N * D * 4);       // 1 MB
  float* acc3 = (float*)(ws + (size_t)N * D * 4 + (size_t)NCHUNK * N * 16);

  hipMemsetAsync(acc3, 0, 3 * sizeof(float), stream);
  cpe_prep<<<N / 4, 256, 0, stream>>>(feat, fhi, flo);
  cpe_main<<<dim3(N / 128, NCHUNK), 256, 0, stream>>>(fhi, flo, labels, partials);
  cpe_rows<<<N / 256, 256, 0, stream>>>(partials, labels, acc3);
  cpe_final<<<1, 1, 0, stream>>>(acc3, out);
}

// Round 2
// 117.240 us; speedup vs baseline: 1.1004x; 1.1004x over previous
//
#include <hip/hip_runtime.h>

#define N 8192
#define D 128
#define CHUNK 512
#define NCHUNK (N / CHUNK)     // 16 column chunks
#define TILE_IT (CHUNK / 128)  // 4 B-tiles per chunk

typedef unsigned short u16;
typedef __attribute__((ext_vector_type(8))) __bf16 bf16x8;
typedef __attribute__((ext_vector_type(4))) float f32x4;

// scale = sqrt(10 * log2(e)): dot of two scaled rows = log2(e^{cos/T}),
// so e^{sim} = exp2(acc) with NO per-element multiply.
#define PREP_SCALE 3.7982889979f

__device__ __forceinline__ u16 f2bf(float x) {
  unsigned u = __float_as_uint(x);
  u += 0x7fff + ((u >> 16) & 1);  // RNE
  return (u16)(u >> 16);
}
__device__ __forceinline__ float bf2f(u16 h) {
  return __uint_as_float(((unsigned)h) << 16);
}

// ---- kernel 1: normalize+scale rows, split fp32 -> bf16 hi+lo; zero acc ----
__global__ __launch_bounds__(256) void cpe_prep(const float* __restrict__ feat,
                                                u16* __restrict__ fhi,
                                                u16* __restrict__ flo,
                                                float* __restrict__ acc3) {
  if (blockIdx.x == 0 && threadIdx.x < 4) acc3[threadIdx.x] = 0.0f;
  const int w = threadIdx.x >> 6, l = threadIdx.x & 63;
  const int row = blockIdx.x * 4 + w;  // one wave per row
  const float2 x = *(const float2*)&feat[row * D + l * 2];
  float s = x.x * x.x + x.y * x.y;
#pragma unroll
  for (int sh = 1; sh < 64; sh <<= 1) s += __shfl_xor(s, sh);
  const float inv = PREP_SCALE / fmaxf(sqrtf(s), 1e-12f);
  const float a = x.x * inv, b = x.y * inv;
  const u16 ah = f2bf(a), bh = f2bf(b);
  const u16 al = f2bf(a - bf2f(ah)), bl = f2bf(b - bf2f(bh));
  *(ushort2*)&fhi[row * D + l * 2] = make_ushort2(ah, bh);
  *(ushort2*)&flo[row * D + l * 2] = make_ushort2(al, bl);
}

// ---- kernel 2: fused sim + masked online reductions ------------------------
// Grid (32, 16): block owns 256 rows x 512-col chunk; wave owns 64 rows.
// bf16x2: sim ~= Ah.Bh + Ah.Bl  (lo_A term dropped, err ~2^-9 relative).
__global__ __launch_bounds__(256, 2) void cpe_main(
    const u16* __restrict__ fhi, const u16* __restrict__ flo,
    const int* __restrict__ labels, float4* __restrict__ partials) {
  __shared__ __align__(16) u16 Bh[128 * 128];  // 32 KB, XOR-swizzled chunks
  __shared__ __align__(16) u16 Bl[128 * 128];  // 32 KB
  __shared__ int Lab[CHUNK];                   // 2 KB
  const int rt = blockIdx.x, cc = blockIdx.y;
  const int tid = threadIdx.x;
  const int w = tid >> 6, l = tid & 63, q = l >> 4, m = l & 15;
  const int r0w = rt * 256 + w * 64;
  const int cbase0 = cc * CHUNK;

  Lab[tid] = labels[cbase0 + tid];
  Lab[tid + 256] = labels[cbase0 + 256 + tid];

  // A fragments + row labels straight from global (L2-resident, once)
  bf16x8 Ah[4][4];
  int labi[4][4];
#pragma unroll
  for (int tr = 0; tr < 4; ++tr) {
    const int row = r0w + tr * 16 + m;
#pragma unroll
    for (int ks = 0; ks < 4; ++ks)
      Ah[tr][ks] = *(const bf16x8*)&fhi[row * D + ks * 32 + q * 8];
#pragma unroll
    for (int v = 0; v < 4; ++v) labi[tr][v] = labels[r0w + tr * 16 + q * 4 + v];
  }

  float mxe[4][4], ps[4][4], as_[4][4];
#pragma unroll
  for (int tr = 0; tr < 4; ++tr)
#pragma unroll
    for (int v = 0; v < 4; ++v) { mxe[tr][v] = 0.f; ps[tr][v] = 0.f; as_[tr][v] = 0.f; }

  for (int it = 0; it < TILE_IT; ++it) {
    const int cbase = cbase0 + it * 128;
    __syncthreads();  // prior reads done (covers Lab for it=0)
    // stage B tile: global->LDS DMA, 16B/lane, swizzle via the GLOBAL addr.
    // LDS chunk p = w*512 + n*64 + lane -> (r = p>>4, c' = p&15=m); c = c'^(r&15).
#pragma unroll
    for (int n = 0; n < 8; ++n) {
      const int r = w * 32 + n * 4 + q;
      const int c = m ^ (r & 15);
      const u16* gh = &fhi[(size_t)(cbase + r) * D + c * 8];
      const u16* gl = &flo[(size_t)(cbase + r) * D + c * 8];
      __builtin_amdgcn_global_load_lds(
          (const __attribute__((address_space(1))) unsigned*)gh,
          (__attribute__((address_space(3))) unsigned*)&Bh[(w * 512 + n * 64) * 8],
          16, 0, 0);
      __builtin_amdgcn_global_load_lds(
          (const __attribute__((address_space(1))) unsigned*)gl,
          (__attribute__((address_space(3))) unsigned*)&Bl[(w * 512 + n * 64) * 8],
          16, 0, 0);
    }
    __syncthreads();  // drains vmcnt

    for (int ct = 0; ct < 8; ++ct) {
      const int jj = ct * 16 + m;
      f32x4 acc[4];
#pragma unroll
      for (int tr = 0; tr < 4; ++tr) acc[tr] = (f32x4){0.f, 0.f, 0.f, 0.f};
#pragma unroll
      for (int ks = 0; ks < 4; ++ks) {
        const int off = jj * 128 + ((ks * 4 + q) ^ m) * 8;  // swizzled chunk
        const bf16x8 bh = *(const bf16x8*)&Bh[off];
        const bf16x8 bl = *(const bf16x8*)&Bl[off];
#pragma unroll
        for (int tr = 0; tr < 4; ++tr)
          acc[tr] = __builtin_amdgcn_mfma_f32_16x16x32_bf16(Ah[tr][ks], bh, acc[tr], 0, 0, 0);
#pragma unroll
        for (int tr = 0; tr < 4; ++tr)
          acc[tr] = __builtin_amdgcn_mfma_f32_16x16x32_bf16(Ah[tr][ks], bl, acc[tr], 0, 0, 0);
      }
      const int labj = Lab[it * 128 + jj];
      const bool fgj = labj >= 0;
      const int jbase = cbase + ct * 16;
#pragma unroll
      for (int tr = 0; tr < 4; ++tr) {
        if (jbase == r0w + tr * 16) {  // wave-uniform diagonal-tile branch
#pragma unroll
          for (int v = 0; v < 4; ++v) {
            const float e = exp2f(acc[tr][v]);
            const float em = (fgj && (m != q * 4 + v)) ? e : 0.0f;
            as_[tr][v] += em;
            mxe[tr][v] = fmaxf(mxe[tr][v], em);
            ps[tr][v] += (labj == labi[tr][v]) ? em : 0.0f;
          }
        } else {
#pragma unroll
          for (int v = 0; v < 4; ++v) {
            const float e = exp2f(acc[tr][v]);
            const float em = fgj ? e : 0.0f;
            as_[tr][v] += em;
            mxe[tr][v] = fmaxf(mxe[tr][v], em);
            ps[tr][v] += (labj == labi[tr][v]) ? em : 0.0f;
          }
        }
      }
    }
  }

  // reduce across the 16 lanes (m) of each quad; rows are (tr, q, v)
#pragma unroll
  for (int tr = 0; tr < 4; ++tr)
#pragma unroll
    for (int v = 0; v < 4; ++v) {
      float vm = mxe[tr][v], vp = ps[tr][v], va = as_[tr][v];
#pragma unroll
      for (int s = 1; s < 16; s <<= 1) {
        vm = fmaxf(vm, __shfl_xor(vm, s));
        vp += __shfl_xor(vp, s);
        va += __shfl_xor(va, s);
      }
      if (m == 0)
        partials[(size_t)cc * N + r0w + tr * 16 + q * 4 + v] =
            make_float4(vm, vp, va, 0.f);
    }
}

// ---- kernel 3: combine partials -> per-row loss -> mean (self-finalizing) --
__global__ __launch_bounds__(256) void cpe_rows(const float4* __restrict__ partials,
                                                const int* __restrict__ labels,
                                                float* __restrict__ acc3,
                                                float* __restrict__ out) {
  const int r = blockIdx.x * 256 + threadIdx.x;
  float mxe = 0.f, ps = 0.f, as_ = 0.f;
#pragma unroll
  for (int c = 0; c < NCHUNK; ++c) {
    const float4 p = partials[(size_t)c * N + r];
    mxe = fmaxf(mxe, p.x); ps += p.y; as_ += p.z;
  }
  // mxe = e^{max_sim}; |sim|<=10 so the +-20 clamp is provably inactive ->
  // exp(-clamped_max) == 1/mxe. pos/all clips replicated exactly.
  const bool fg = labels[r] >= 0;
  const bool valid = fg && (ps > 0.f);  // e>0 => (np>0 <=> ps>0)
  const float pos = fminf(fmaxf(ps / mxe, 1e-6f), 1e6f);
  const float all = fminf(fmaxf(as_ / mxe, 1e-6f), 1e6f);
  const float loss = fminf(-logf(pos / all), 10.0f);
  float v0 = valid ? loss : 0.f;
  float v1 = valid ? 1.f : 0.f;
  float v2 = fg ? 1.f : 0.f;
#pragma unroll
  for (int s = 1; s < 64; s <<= 1) {
    v0 += __shfl_xor(v0, s); v1 += __shfl_xor(v1, s); v2 += __shfl_xor(v2, s);
  }
  __shared__ float red[3][4];
  const int w = threadIdx.x >> 6, l = threadIdx.x & 63;
  if (l == 0) { red[0][w] = v0; red[1][w] = v1; red[2][w] = v2; }
  __syncthreads();
  if (threadIdx.x == 0) {
    atomicAdd(&acc3[0], red[0][0] + red[0][1] + red[0][2] + red[0][3]);
    atomicAdd(&acc3[1], red[1][0] + red[1][1] + red[1][2] + red[1][3]);
    atomicAdd(&acc3[2], red[2][0] + red[2][1] + red[2][2] + red[2][3]);
    __threadfence();
    const unsigned old = atomicAdd((unsigned*)&acc3[3], 1u);
    if (old == gridDim.x - 1) {  // last block finalizes (device-scope reads)
      const float ls = atomicAdd(&acc3[0], 0.0f);
      const float nv = atomicAdd(&acc3[1], 0.0f);
      const float nf = atomicAdd(&acc3[2], 0.0f);
      out[0] = (nf >= 2.0f && nv > 0.0f) ? ls / fmaxf(nv, 1.0f) : 0.0f;
    }
  }
}

extern "C" void kernel_launch(void* const* d_in, const int* in_sizes, int n_in,
                              void* d_out, int out_size, void* d_ws, size_t ws_size,
                              hipStream_t stream) {
  const float* feat = (const float*)d_in[0];
  const int* labels = (const int*)d_in[1];
  float* out = (float*)d_out;
  char* ws = (char*)d_ws;
  u16* fhi = (u16*)ws;                                      // 2 MB
  u16* flo = (u16*)(ws + (size_t)N * D * 2);                // 2 MB
  float4* partials = (float4*)(ws + (size_t)N * D * 4);     // 2 MB
  float* acc3 = (float*)(ws + (size_t)N * D * 4 + (size_t)NCHUNK * N * 16);

  cpe_prep<<<N / 4, 256, 0, stream>>>(feat, fhi, flo, acc3);
  cpe_main<<<dim3(N / 256, NCHUNK), 256, 0, stream>>>(fhi, flo, labels, partials);
  cpe_rows<<<N / 256, 256, 0, stream>>>(partials, labels, acc3, out);
}